// Round 3
// baseline (12823.128 us; speedup 1.0000x reference)
//
#include <hip/hip_runtime.h>
#include <math.h>

#define BSZ 32
#define TT  32
#define XD  128
#define HD  512
#define VT  2048
#define WD  64
#define RDM 4
#define NDM 1024
#define ET  463
#define GKS 8
#define VKS 16

typedef unsigned long long ull;

__device__ __forceinline__ float sigf(float x){ return 1.f/(1.f+expf(-x)); }
__device__ __forceinline__ float logsigf(float x){
    return (x >= 0.f) ? -log1pf(expf(-x)) : x - log1pf(expf(x));
}

// block-wide reductions for 1024 threads (16 waves), wave64 shuffle + 16-slot LDS
__device__ __forceinline__ float bsum(float v, float* wred){
    #pragma unroll
    for (int o = 32; o > 0; o >>= 1) v += __shfl_xor(v, o);
    int lane = threadIdx.x & 63, wid = threadIdx.x >> 6;
    if (lane == 0) wred[wid] = v;
    __syncthreads();
    if (wid == 0){
        float s = (lane < 16) ? wred[lane] : 0.f;
        #pragma unroll
        for (int o = 8; o > 0; o >>= 1) s += __shfl_xor(s, o);
        if (lane == 0) wred[0] = s;
    }
    __syncthreads();
    float r = wred[0];
    __syncthreads();
    return r;
}
__device__ __forceinline__ float bmax(float v, float* wred){
    #pragma unroll
    for (int o = 32; o > 0; o >>= 1) v = fmaxf(v, __shfl_xor(v, o));
    int lane = threadIdx.x & 63, wid = threadIdx.x >> 6;
    if (lane == 0) wred[wid] = v;
    __syncthreads();
    if (wid == 0){
        float s = (lane < 16) ? wred[lane] : -3.4e38f;
        #pragma unroll
        for (int o = 8; o > 0; o >>= 1) s = fmaxf(s, __shfl_xor(s, o));
        if (lane == 0) wred[0] = s;
    }
    __syncthreads();
    float r = wred[0];
    __syncthreads();
    return r;
}

// ---------------- batchnorm for ALL timesteps (depends only on x) -------------------
__global__ void dnc_bn_all(const float* __restrict__ x, float* __restrict__ xbn){
    int t = blockIdx.x, f = threadIdx.x;
    if (f >= XD) return;
    float vals[BSZ]; float s = 0.f;
    #pragma unroll
    for (int b = 0; b < BSZ; ++b){ vals[b] = x[(b*TT + t)*XD + f]; s += vals[b]; }
    float mean = s * (1.f/BSZ);
    float ss = 0.f;
    #pragma unroll
    for (int b = 0; b < BSZ; ++b){ float d = vals[b]-mean; ss += d*d; }
    float inv = 1.f / sqrtf(ss*(1.f/BSZ) + 1e-5f);
    #pragma unroll
    for (int b = 0; b < BSZ; ++b) xbn[(t*BSZ + b)*XD + f] = (vals[b]-mean)*inv;
}

// ---------------- LSTM pre-activation GEMM, 3-source K layout -----------------------
// K layout: [srcA (cA chunks) | srcB (cB chunks) | h (8 chunks)] ; Wih covers A+B, Whh covers h.
__global__ void dnc_lstm_gemm3(const float* __restrict__ srcA, int stA, int cA,
                               const float* __restrict__ srcB, int stB, int cB,
                               const float* __restrict__ hsrc,
                               const float* __restrict__ Wih, int Kih,
                               const float* __restrict__ Whh,
                               float* __restrict__ gpart){
    const int jc = blockIdx.x, d = blockIdx.y, ks = blockIdx.z;
    const int tid = threadIdx.x;
    const int jg = tid & 31, bg = tid >> 5;
    const int j0 = jc*128 + jg*4;
    const int b0 = bg*4;
    const int cAB = cA + cB;
    const int nct = cAB + 8;
    const int per = (nct + GKS - 1) / GKS;
    int c0 = ks*per; int c1 = min(nct, c0+per);
    __shared__ __align__(16) float tile[64*36];
    float acc[4][4] = {{0}};
    for (int c = c0; c < c1; ++c){
        const float* src; int stride, kb; const float* Wb; int Kw; int kcol;
        if (c < cA){ src = srcA; stride = stA; kb = c*64; Wb = Wih + (size_t)d*2048*Kih; Kw = Kih; kcol = c*64; }
        else if (c < cAB){ src = srcB; stride = stB; kb = (c-cA)*64; Wb = Wih + (size_t)d*2048*Kih; Kw = Kih; kcol = c*64; }
        else { src = hsrc + d*(BSZ*HD); stride = HD; kb = (c-cAB)*64; Wb = Whh + (size_t)d*2048*512; Kw = 512; kcol = kb; }
        #pragma unroll
        for (int i = 0; i < 8; ++i){
            int idx = i*256 + tid; int kk = idx & 63, b = idx >> 6;
            tile[kk*36 + b] = src[b*stride + kb + kk];
        }
        __syncthreads();
        const float* w0p = Wb + (size_t)(j0+0)*Kw + kcol;
        const float* w1p = Wb + (size_t)(j0+1)*Kw + kcol;
        const float* w2p = Wb + (size_t)(j0+2)*Kw + kcol;
        const float* w3p = Wb + (size_t)(j0+3)*Kw + kcol;
        #pragma unroll
        for (int kk = 0; kk < 64; kk += 4){
            float4 a0 = *(const float4*)&tile[(kk+0)*36 + b0];
            float4 a1 = *(const float4*)&tile[(kk+1)*36 + b0];
            float4 a2 = *(const float4*)&tile[(kk+2)*36 + b0];
            float4 a3 = *(const float4*)&tile[(kk+3)*36 + b0];
            float4 w;
            #define ACCJ(JJ, WP) \
                w = *(const float4*)(WP + kk); \
                acc[JJ][0] += a0.x*w.x + a1.x*w.y + a2.x*w.z + a3.x*w.w; \
                acc[JJ][1] += a0.y*w.x + a1.y*w.y + a2.y*w.z + a3.y*w.w; \
                acc[JJ][2] += a0.z*w.x + a1.z*w.y + a2.z*w.z + a3.z*w.w; \
                acc[JJ][3] += a0.w*w.x + a1.w*w.y + a2.w*w.z + a3.w*w.w;
            ACCJ(0, w0p) ACCJ(1, w1p) ACCJ(2, w2p) ACCJ(3, w3p)
            #undef ACCJ
        }
        __syncthreads();
    }
    #pragma unroll
    for (int jj = 0; jj < 4; ++jj){
        #pragma unroll
        for (int bb = 0; bb < 4; ++bb)
            gpart[((size_t)(d*GKS + ks)*BSZ + (b0+bb))*2048 + (j0+jj)] = acc[jj][bb];
    }
}

// ---------------- LSTM gates -> h, c ------------------------------------------------
__global__ void dnc_gates(const float* __restrict__ gpart,
                          const float* __restrict__ bih, const float* __restrict__ bhh,
                          float* __restrict__ cstate, float* __restrict__ hstate,
                          float* __restrict__ flat, float* __restrict__ lout, int l){
    int idx = blockIdx.x*256 + threadIdx.x;
    int u = idx & 511, b = (idx >> 9) & 31, d = idx >> 14;
    int cell = 2*l + d;
    float g[4];
    #pragma unroll
    for (int xg = 0; xg < 4; ++xg){
        int j = xg*512 + u;
        float s = bih[d*2048 + j] + bhh[d*2048 + j];
        #pragma unroll
        for (int ks = 0; ks < GKS; ++ks)
            s += gpart[((size_t)(d*GKS + ks)*BSZ + b)*2048 + j];
        g[xg] = s;
    }
    float ig = sigf(g[0]), fg = sigf(g[1]), og = sigf(g[3]);
    float gg = tanhf(g[2]);
    int ci = (cell*BSZ + b)*HD + u;
    float c2 = fg*cstate[ci] + ig*gg;
    cstate[ci] = c2;
    float h = og*tanhf(c2);
    hstate[ci] = h;
    flat[b*2048 + cell*HD + u] = h;
    if (lout) lout[b*1024 + d*HD + u] = h;
}

// ---------------- combined GEMV: flat@Wy (->vtp) and flat@WE (->ep), k-split --------
__global__ void dnc_gemv2(const float* __restrict__ fin, const float* __restrict__ Wy,
                          const float* __restrict__ WE,
                          float* __restrict__ vtp, float* __restrict__ ep){
    const int mbi = blockIdx.x, ksi = blockIdx.y;
    const float* Wm; float* outp; int Mdim, mb;
    if (mbi < 16){ Wm = Wy; outp = vtp; Mdim = VT; mb = mbi; }
    else        { Wm = WE; outp = ep;  Mdim = ET; mb = mbi - 16; }
    const int tid = threadIdx.x;
    const int lane = tid & 63, bg = tid >> 6;
    const int b0 = bg*8;
    const int m0 = mb*128 + lane, m1 = m0 + 64;
    const int k0 = ksi*128;
    __shared__ __align__(16) float tile[128*36];
    #pragma unroll
    for (int i = 0; i < 16; ++i){
        int idx = i*256 + tid; int kk = idx & 127, b = idx >> 7;
        tile[kk*36 + b] = fin[b*2048 + k0 + kk];
    }
    __syncthreads();
    bool v0 = m0 < Mdim, v1 = m1 < Mdim;
    float acc[16] = {0};
    for (int kk = 0; kk < 128; ++kk){
        float4 pq = *(const float4*)&tile[kk*36 + b0];
        float4 qq = *(const float4*)&tile[kk*36 + b0 + 4];
        const float* wr = Wm + (size_t)(k0+kk)*Mdim;
        float w0 = v0 ? wr[m0] : 0.f;
        float w1 = v1 ? wr[m1] : 0.f;
        acc[0]+=pq.x*w0; acc[1]+=pq.y*w0; acc[2]+=pq.z*w0; acc[3]+=pq.w*w0;
        acc[4]+=qq.x*w0; acc[5]+=qq.y*w0; acc[6]+=qq.z*w0; acc[7]+=qq.w*w0;
        acc[8]+=pq.x*w1; acc[9]+=pq.y*w1; acc[10]+=pq.z*w1; acc[11]+=pq.w*w1;
        acc[12]+=qq.x*w1; acc[13]+=qq.y*w1; acc[14]+=qq.z*w1; acc[15]+=qq.w*w1;
    }
    if (v0){
        #pragma unroll
        for (int bb = 0; bb < 8; ++bb)
            outp[((size_t)ksi*BSZ + b0+bb)*Mdim + m0] = acc[bb];
    }
    if (v1){
        #pragma unroll
        for (int bb = 0; bb < 8; ++bb)
            outp[((size_t)ksi*BSZ + b0+bb)*Mdim + m1] = acc[8+bb];
    }
}

// ---------------- fused memory model: one block per batch element -------------------
// ln -> usage -> sort+alloc -> cw score/softmax/ww -> mem update -> rd score/softmax
// -> read vectors. All intermediates in LDS/registers.
__global__ __launch_bounds__(1024) void dnc_mem(
    const float* __restrict__ ep, float* __restrict__ lrw, float* __restrict__ lww,
    float* __restrict__ ubuf, float* __restrict__ M, float* __restrict__ lrv){
    const int b = blockIdx.x, tid = threadIdx.x;
    __shared__ float buf[464];
    __shared__ float wred[16];
    __shared__ float nrm4[4];
    __shared__ float ers[64];
    __shared__ float red[1024];
    __shared__ ull   keys[1024];
    __shared__ float pa[1024], pb[1024];
    __shared__ float p4[4096];

    // ---- phase 1: layernorm of interface vector ----
    float v = 0.f;
    if (tid < ET){
        #pragma unroll
        for (int s = 0; s < VKS; ++s) v += ep[((size_t)s*BSZ + b)*ET + tid];
    }
    float mean = bsum(v, wred) * (1.f/ET);
    float dv = (tid < ET) ? (v - mean) : 0.f;
    float var = bsum(dv*dv, wred) * (1.f/ET);
    float rinv = 1.f / sqrtf(var + 1e-5f);
    if (tid < ET) buf[tid] = dv * rinv;
    __syncthreads();
    if (tid < 64) ers[tid] = sigf(buf[325 + tid]);   // erase vector (shared)

    // ---- phase 2: usage update ----
    const int n = tid;
    float4 lw4 = *(const float4*)&lrw[((size_t)b*1024 + n)*4];
    float f0 = sigf(buf[453]), f1 = sigf(buf[454]), f2 = sigf(buf[455]), f3 = sigf(buf[456]);
    float ret = (1.f - f0*lw4.x)*(1.f - f1*lw4.y)*(1.f - f2*lw4.z)*(1.f - f3*lw4.w);
    float uo = ubuf[b*1024 + n], lwo = lww[b*1024 + n];
    float un = (uo + lwo - uo*lwo) * ret;
    ubuf[b*1024 + n] = un;

    // ---- phase 3: stable ascending argsort (bitonic on (bits<<32)|idx) + alloc ----
    keys[tid] = ((ull)__float_as_uint(un) << 32) | (unsigned)tid;
    __syncthreads();
    for (int k = 2; k <= 1024; k <<= 1){
        for (int j = k >> 1; j > 0; j >>= 1){
            int ixj = tid ^ j;
            if (ixj > tid){
                ull a = keys[tid], c = keys[ixj];
                bool up = ((tid & k) == 0);
                if ((a > c) == up){ keys[tid] = c; keys[ixj] = a; }
            }
            __syncthreads();
        }
    }
    ull kv = keys[tid];
    float su = __uint_as_float((unsigned)(kv >> 32));
    int idxv = (int)(kv & 0xffffffffu);
    pa[tid] = su;
    __syncthreads();
    float* sA = pa; float* sB = pb;
    for (int off = 1; off < 1024; off <<= 1){
        float vv = sA[tid];
        if (tid >= off) vv *= sA[tid - off];
        sB[tid] = vv;
        __syncthreads();
        float* tmp = sA; sA = sB; sB = tmp;
    }
    float cp = (tid == 0) ? 1.f : sA[tid - 1];
    red[idxv] = (1.f - su) * cp;      // scatter back to unsorted order
    __syncthreads();
    float alloc = red[n];

    // ---- phase 4: content write score + softmax + write weighting ----
    float ksq = 0.f;
    #pragma unroll
    for (int w = 0; w < 64; ++w){ float kk = buf[260 + w]; ksq += kk*kk; }
    float kden = sqrtf(ksq) + 1e-8f;
    float wbeta = 1.f - logsigf(buf[324]);
    float4* Mr4 = (float4*)(M + ((size_t)b*1024 + n)*64);
    float dot = 0.f, msq = 0.f;
    #pragma unroll
    for (int i = 0; i < 16; ++i){
        float4 mv = Mr4[i];
        int w0 = i*4;
        dot += mv.x*buf[260+w0] + mv.y*buf[260+w0+1] + mv.z*buf[260+w0+2] + mv.w*buf[260+w0+3];
        msq += mv.x*mv.x + mv.y*mv.y + mv.z*mv.z + mv.w*mv.w;
    }
    float sc = wbeta * dot / ((sqrtf(msq) + 1e-8f) * kden);
    float mx = bmax(sc, wred);
    float ex = expf(sc - mx);
    float tot = bsum(ex, wred);
    float cwv = ex / tot;
    float ag = sigf(buf[457]), wg = sigf(buf[458]);
    float ww = wg * (ag*alloc + (1.f - ag)*cwv);
    lww[b*1024 + n] = ww;

    // ---- phase 5: memory update + row norm ----
    float msq2 = 0.f;
    #pragma unroll
    for (int i = 0; i < 16; ++i){
        float4 mv = Mr4[i];
        int w0 = i*4;
        mv.x = mv.x*(1.f - ww*ers[w0  ]) + ww*buf[389+w0  ];
        mv.y = mv.y*(1.f - ww*ers[w0+1]) + ww*buf[389+w0+1];
        mv.z = mv.z*(1.f - ww*ers[w0+2]) + ww*buf[389+w0+2];
        mv.w = mv.w*(1.f - ww*ers[w0+3]) + ww*buf[389+w0+3];
        msq2 += mv.x*mv.x + mv.y*mv.y + mv.z*mv.z + mv.w*mv.w;
        Mr4[i] = mv;
    }
    float den = sqrtf(msq2) + 1e-8f;

    // ---- phase 6: normalize read keys in-place (buf[0:256]) ----
    float rb0 = 1.f - logsigf(buf[256]);
    float rb1 = 1.f - logsigf(buf[257]);
    float rb2 = 1.f - logsigf(buf[258]);
    float rb3 = 1.f - logsigf(buf[259]);
    if (tid < 4){
        float s = 0.f;
        #pragma unroll
        for (int w = 0; w < 64; ++w){ float q = buf[w*4 + tid]; s += q*q; }
        nrm4[tid] = sqrtf(s) + 1e-8f;
    }
    __syncthreads();
    float scaled = 0.f;
    if (tid < 256) scaled = buf[tid] / nrm4[tid & 3];
    __syncthreads();
    if (tid < 256) buf[tid] = scaled;
    __syncthreads();

    // ---- phase 7: read scores (4 heads) ----
    float d0 = 0.f, d1 = 0.f, d2 = 0.f, d3 = 0.f;
    #pragma unroll
    for (int i = 0; i < 16; ++i){
        float4 mv = Mr4[i];
        int w0 = i*4;
        d0 += mv.x*buf[(w0  )*4+0] + mv.y*buf[(w0+1)*4+0] + mv.z*buf[(w0+2)*4+0] + mv.w*buf[(w0+3)*4+0];
        d1 += mv.x*buf[(w0  )*4+1] + mv.y*buf[(w0+1)*4+1] + mv.z*buf[(w0+2)*4+1] + mv.w*buf[(w0+3)*4+1];
        d2 += mv.x*buf[(w0  )*4+2] + mv.y*buf[(w0+1)*4+2] + mv.z*buf[(w0+2)*4+2] + mv.w*buf[(w0+3)*4+2];
        d3 += mv.x*buf[(w0  )*4+3] + mv.y*buf[(w0+1)*4+3] + mv.z*buf[(w0+2)*4+3] + mv.w*buf[(w0+3)*4+3];
    }
    float vr[4];
    vr[0] = rb0*d0/den; vr[1] = rb1*d1/den; vr[2] = rb2*d2/den; vr[3] = rb3*d3/den;

    // ---- phase 8: read softmaxes -> p ----
    float pr[4];
    #pragma unroll
    for (int r = 0; r < 4; ++r){
        float m2 = bmax(vr[r], wred);
        float e2 = expf(vr[r] - m2);
        float t2 = bsum(e2, wred);
        pr[r] = e2 / t2;
    }
    float4 pv = make_float4(pr[0], pr[1], pr[2], pr[3]);
    *(float4*)&p4[n*4] = pv;
    *(float4*)&lrw[((size_t)b*1024 + n)*4] = pv;
    __syncthreads();

    // ---- phase 9: read vectors rv[w][r] = sum_n M[n][w] * p[n][r] ----
    int w = tid & 63, rr = (tid >> 6) & 3, sl = tid >> 8;
    float acc = 0.f;
    const float* Mb = M + (size_t)b*1024*64;
    for (int i = 0; i < 256; ++i){
        int n2 = sl*256 + i;
        acc += Mb[(size_t)n2*64 + w] * p4[n2*4 + rr];
    }
    red[tid] = acc;
    __syncthreads();
    if (tid < 256){
        float s = red[tid] + red[tid+256] + red[tid+512] + red[tid+768];
        lrv[b*256 + (tid & 63)*4 + (tid >> 6)] = s;   // layout [b][w*4+r]
    }
}

// ---------------- rv @ Wr partials ---------------------------------------------------
__global__ void dnc_ywr(const float* __restrict__ lrv, const float* __restrict__ Wr,
                        float* __restrict__ ywrp){
    int mb = blockIdx.x, ks = blockIdx.y, tid = threadIdx.x;
    int m = mb*256 + tid, k0 = ks*64;
    __shared__ float rvf[32*64];
    #pragma unroll
    for (int i = 0; i < 8; ++i){
        int idx = i*256 + tid; int b = idx >> 6, kk = idx & 63;
        rvf[b*64 + kk] = lrv[b*256 + k0 + kk];
    }
    __syncthreads();
    float acc[32];
    #pragma unroll
    for (int b = 0; b < 32; ++b) acc[b] = 0.f;
    for (int kk = 0; kk < 64; ++kk){
        float wv = Wr[(size_t)(k0+kk)*VT + m];
        #pragma unroll
        for (int b = 0; b < 32; ++b) acc[b] += rvf[b*64 + kk]*wv;
    }
    #pragma unroll
    for (int b = 0; b < 32; ++b) ywrp[((size_t)(ks*BSZ + b))*VT + m] = acc[b];
}

// ---------------- final: yt = sum partials; out = max over t -------------------------
__global__ void dnc_yt_fin(const float* __restrict__ vtp, const float* __restrict__ ywrp,
                           float* __restrict__ out, int t){
    int idx = blockIdx.x*256 + threadIdx.x;
    int b = idx >> 11, m = idx & 2047;
    float acc = 0.f;
    #pragma unroll
    for (int s = 0; s < VKS; ++s) acc += vtp[((size_t)s*BSZ + b)*VT + m];
    #pragma unroll
    for (int ks = 0; ks < 4; ++ks) acc += ywrp[((size_t)(ks*BSZ + b))*VT + m];
    if (t == 0) out[idx] = acc;
    else out[idx] = fmaxf(out[idx], acc);
}

extern "C" void kernel_launch(void* const* d_in, const int* in_sizes, int n_in,
                              void* d_out, int out_size, void* d_ws, size_t ws_size,
                              hipStream_t stream){
    const float* x      = (const float*)d_in[0];
    const float* mem0   = (const float*)d_in[1];
    const float* Wy     = (const float*)d_in[2];
    const float* WE     = (const float*)d_in[3];
    const float* Wr     = (const float*)d_in[4];
    const float* Wih0   = (const float*)d_in[5];
    const float* Whh0   = (const float*)d_in[6];
    const float* bih0   = (const float*)d_in[7];
    const float* bhh0   = (const float*)d_in[8];
    const float* Wih1   = (const float*)d_in[9];
    const float* Whh1   = (const float*)d_in[10];
    const float* bih1   = (const float*)d_in[11];
    const float* bhh1   = (const float*)d_in[12];
    float* out = (float*)d_out;

    float* p = (float*)d_ws;
    float* M      = p; p += (size_t)32*1024*64;
    float* hstate = p; p += 4*32*512;     // zero block start
    float* cstate = p; p += 4*32*512;
    float* ubuf   = p; p += 32*1024;
    float* lww    = p; p += 32*1024;
    float* lrw    = p; p += 32*1024*4;
    float* lrv    = p; p += 32*256;       // zero block end
    float* xbn    = p; p += (size_t)TT*BSZ*XD;
    float* lin1   = p; p += 32*1024;
    float* gpart  = p; p += (size_t)2*GKS*32*2048;
    float* flat   = p; p += 32*2048;
    float* vtp    = p; p += (size_t)VKS*32*2048;
    float* ep     = p; p += (size_t)VKS*32*ET;
    float* ywrp   = p; p += (size_t)4*32*2048;

    (void)hipMemcpyAsync(M, mem0, (size_t)32*1024*64*sizeof(float), hipMemcpyDeviceToDevice, stream);
    size_t zfloats = (size_t)(4*32*512)*2 + 32*1024*2 + 32*1024*4 + 32*256;
    (void)hipMemsetAsync(hstate, 0, zfloats*sizeof(float), stream);

    dnc_bn_all<<<TT, 128, 0, stream>>>(x, xbn);

    for (int t = 0; t < TT; ++t){
        dnc_lstm_gemm3<<<dim3(16,2,GKS), 256, 0, stream>>>(
            xbn + (size_t)t*BSZ*XD, XD, 2, lrv, 256, 4, hstate, Wih0, 384, Whh0, gpart);
        dnc_gates<<<128, 256, 0, stream>>>(gpart, bih0, bhh0, cstate, hstate, flat, lin1, 0);
        dnc_lstm_gemm3<<<dim3(16,2,GKS), 256, 0, stream>>>(
            lin1, 1024, 16, nullptr, 0, 0, hstate + 2*32*512, Wih1, 1024, Whh1, gpart);
        dnc_gates<<<128, 256, 0, stream>>>(gpart, bih1, bhh1, cstate, hstate, flat, nullptr, 1);
        dnc_gemv2<<<dim3(20,VKS), 256, 0, stream>>>(flat, Wy, WE, vtp, ep);
        dnc_mem<<<32, 1024, 0, stream>>>(ep, lrw, lww, ubuf, M, lrv);
        dnc_ywr<<<dim3(8,4), 256, 0, stream>>>(lrv, Wr, ywrp);
        dnc_yt_fin<<<256, 256, 0, stream>>>(vtp, ywrp, out, t);
    }
}